// Round 3
// baseline (279.861 us; speedup 1.0000x reference)
//
#include <hip/hip_runtime.h>

#define BLK 256
#define LBLK 256   // layer kernel: 16 threads per node, 16 nodes/block
#define CH 1024    // scan chunk per block (N=200000 -> 196 blocks, <= 256)

// ---------------- bf16 helpers ----------------
__device__ __forceinline__ unsigned short f2bf(float f) {
    unsigned u = __float_as_uint(f);
    u += 0x7FFFu + ((u >> 16) & 1u);       // round-to-nearest-even
    return (unsigned short)(u >> 16);
}
__device__ __forceinline__ float bf2f(unsigned short h) {
    return __uint_as_float((unsigned)h << 16);
}
__device__ __forceinline__ float4 unpack4(ushort4 h) {
    return make_float4(bf2f(h.x), bf2f(h.y), bf2f(h.z), bf2f(h.w));
}
__device__ __forceinline__ ushort4 pack4(float4 f) {
    ushort4 h; h.x = f2bf(f.x); h.y = f2bf(f.y); h.z = f2bf(f.z); h.w = f2bf(f.w);
    return h;
}

// ---------------- setup kernels ----------------

// count degree by dst AND record each edge's rank within its dst row
__global__ void k_deg(const int* __restrict__ dst, int* __restrict__ deg,
                      int* __restrict__ rank, int E) {
    int e = blockIdx.x * blockDim.x + threadIdx.x;
    if (e < E) rank[e] = atomicAdd(&deg[dst[e]], 1);
}

// per-chunk sums (int4 loads, one reduce per block)
__global__ void k_scan1(const int* __restrict__ deg, int* __restrict__ partials, int N) {
    __shared__ int sm[BLK];
    int i0 = blockIdx.x * CH + threadIdx.x * 4;
    int s = 0;
    if (i0 + 3 < N) {
        int4 v = *(const int4*)(deg + i0);
        s = (v.x + v.y) + (v.z + v.w);
    } else {
        for (int k = 0; k < 4; ++k) if (i0 + k < N) s += deg[i0 + k];
    }
    sm[threadIdx.x] = s;
    __syncthreads();
    for (int off = BLK / 2; off > 0; off >>= 1) {
        if (threadIdx.x < off) sm[threadIdx.x] += sm[threadIdx.x + off];
        __syncthreads();
    }
    if (threadIdx.x == 0) partials[blockIdx.x] = sm[0];
}

// fused: redundant scan of partials for block base, then one vectorized
// LDS-scan tile over this block's 1024-element chunk -> row_off
__global__ void k_scan2(const int* __restrict__ deg, const int* __restrict__ partials,
                        int* __restrict__ row_off, int N, int E, int nb) {
    __shared__ int sp[BLK];
    __shared__ int sm[BLK];
    int b = blockIdx.x, t = threadIdx.x;
    sp[t] = (t < nb) ? partials[t] : 0;
    __syncthreads();
    for (int off = 1; off < BLK; off <<= 1) {
        int add = (t >= off) ? sp[t - off] : 0;
        __syncthreads();
        sp[t] += add;
        __syncthreads();
    }
    int base = (b == 0) ? 0 : sp[b - 1];
    if (b == 0 && t == 0) row_off[N] = E;
    int i0 = b * CH + t * 4;
    int v0 = 0, v1 = 0, v2 = 0, v3 = 0;
    if (i0 + 3 < N) {
        int4 v = *(const int4*)(deg + i0);
        v0 = v.x; v1 = v.y; v2 = v.z; v3 = v.w;
    } else {
        if (i0     < N) v0 = deg[i0];
        if (i0 + 1 < N) v1 = deg[i0 + 1];
        if (i0 + 2 < N) v2 = deg[i0 + 2];
    }
    int tot = (v0 + v1) + (v2 + v3);
    sm[t] = tot;
    __syncthreads();
    for (int off = 1; off < BLK; off <<= 1) {
        int add = (t >= off) ? sm[t - off] : 0;
        __syncthreads();
        sm[t] += add;
        __syncthreads();
    }
    int excl = base + sm[t] - tot;
    int4 r;
    r.x = excl;
    r.y = excl + v0;
    r.z = excl + v0 + v1;
    r.w = excl + v0 + v1 + v2;
    if (i0 + 3 < N) {
        *(int4*)(row_off + i0) = r;
    } else {
        if (i0     < N) row_off[i0]     = r.x;
        if (i0 + 1 < N) row_off[i0 + 1] = r.y;
        if (i0 + 2 < N) row_off[i0 + 2] = r.z;
    }
}

// fused conv + fill (independent jobs, one dispatch):
//  blocks [0,gF): atomic-free CSR fill, 8B records {src, bf16 a | bf16 r << 16}
//                 rank<4 edges ALSO mirrored into f4[dst*4+rank] (direct-indexed
//                 first-4 table -> layer kernel gets a 2-level dependent chain)
//  blocks [gF,..): embs[v] = bf16(dinv[v] * emb[v])
__global__ void k_convfill(const int* __restrict__ src, const int* __restrict__ dst,
                           const float2* __restrict__ attrs, const int* __restrict__ row_off,
                           const int* __restrict__ rank, const int* __restrict__ deg,
                           uint2* __restrict__ csr, uint2* __restrict__ f4,
                           const float4* __restrict__ emb4,
                           ushort4* __restrict__ embs, int E, int N16, int gF) {
    int b = blockIdx.x;
    if (b < gF) {
        int e = b * BLK + threadIdx.x;
        if (e >= E) return;
        int d  = dst[e];
        int rk = rank[e];
        float2 ar = attrs[e];
        uint2 rec = make_uint2((unsigned)src[e],
                               (unsigned)f2bf(ar.x) | ((unsigned)f2bf(ar.y) << 16));
        csr[row_off[d] + rk] = rec;
        if (rk < 4) f4[(size_t)d * 4 + rk] = rec;
    } else {
        int i = (b - gF) * BLK + threadIdx.x;
        if (i >= N16) return;
        int dg = deg[i >> 4];
        float dinv = (dg > 0) ? rsqrtf((float)dg) : 0.0f;
        float4 e = emb4[i];
        embs[i] = pack4(make_float4(dinv * e.x, dinv * e.y, dinv * e.z, dinv * e.w));
    }
}

// ---------------- per-layer kernel ----------------
// 16 threads per node, 4 dims each (bf16x4).
// Chain-shortening: f4[v] (first 4 edge records, direct-indexed) and
// row_off[v..v+1] load in PARALLEL (level 0); first-round gathers issue after
// ONE round trip (level 1). deg<=4 (89% of nodes) never touches csr.
// deg 5..8 (9%): csr loads for round 1 overlap round-0 gathers. deg>8 loops.
// f4 is zero-filled for missing slots: src=0 (valid row), ar=0 -> w=1 (finite),
// masked out by g. xs rows PRE-SCALED by dinv[src].
// x_new[v] = dinv[v] * (Σ w·xs[src]) / (Σ w + eps)

__device__ __forceinline__ float lrelu(float x) { return fmaxf(x, 0.01f * x); }

__device__ __forceinline__ float4 edge_w4(unsigned ar, const float4& aw, const float4& rw) {
    float a = bf2f((unsigned short)(ar & 0xffffu));
    float r = bf2f((unsigned short)(ar >> 16));
    float4 w;
    w.x = __expf(lrelu(a * aw.x) + lrelu(r * rw.x));
    w.y = __expf(lrelu(a * aw.y) + lrelu(r * rw.y));
    w.z = __expf(lrelu(a * aw.z) + lrelu(r * rw.z));
    w.w = __expf(lrelu(a * aw.w) + lrelu(r * rw.w));
    return w;
}

__device__ __forceinline__ void acc4(float4& num, float4& den,
                                     const float4& w, const ushort4& h, float g) {
    float4 x = unpack4(h);
    den.x += g * w.x; den.y += g * w.y; den.z += g * w.z; den.w += g * w.w;
    num.x += g * w.x * x.x;
    num.y += g * w.y * x.y;
    num.z += g * w.z * x.z;
    num.w += g * w.w * x.w;
}

template<int MODE>
__global__ __launch_bounds__(LBLK) void k_layer(
    const ushort4* __restrict__ xs, const uint2* __restrict__ csr,
    const uint2* __restrict__ f4, const int* __restrict__ row_off,
    const float4* __restrict__ aw4, const float4* __restrict__ rw4,
    const float4* __restrict__ emb4,
    const ushort4* __restrict__ xsA, const ushort4* __restrict__ xsB,
    ushort4* __restrict__ xsout, float4* __restrict__ out4, int N) {
    const int t = threadIdx.x;
    const int d4 = t & 15;
    const int v = blockIdx.x * (LBLK / 16) + (t >> 4);
    if (v >= N) return;
    const unsigned nm1 = (unsigned)(N - 1);
    const size_t o = (size_t)v * 16 + d4;

    const float4 aw = aw4[d4];
    const float4 rw = rw4[d4];

    // ---- level 0: all independent of memory (only v) ----
    const uint4 fa = *(const uint4*)(f4 + (size_t)v * 4);      // src0,ar0,src1,ar1
    const uint4 fb = *(const uint4*)(f4 + (size_t)v * 4 + 2);  // src2,ar2,src3,ar3
    const int s0 = row_off[v];
    const int s1 = row_off[v + 1];

    // MODE2 sequential per-node loads hoisted to overlap the gather chain
    float4 emb_v = {0,0,0,0}, Av = {0,0,0,0}, Bv = {0,0,0,0};
    if (MODE == 2) {
        emb_v = emb4[o];
        Av = unpack4(xsA[o]);
        Bv = unpack4(xsB[o]);
    }

    // ---- level 1: first-round gathers (dep: fa/fb only) ----
    ushort4 h0 = xs[(size_t)min(fa.x, nm1) * 16 + d4];
    ushort4 h1 = xs[(size_t)min(fa.z, nm1) * 16 + d4];
    ushort4 h2 = xs[(size_t)min(fb.x, nm1) * 16 + d4];
    ushort4 h3 = xs[(size_t)min(fb.z, nm1) * 16 + d4];

    float4 num = {0.f, 0.f, 0.f, 0.f};
    float4 den = {0.f, 0.f, 0.f, 0.f};

    // round 1 (deg 5..8, ~9% of nodes; csr loads overlap round-0 gathers)
    if (s0 + 4 < s1) {
        const int l = max(s1 - 1, 0);      // always a valid finite csr slot
        uint2 e4 = csr[min(s0 + 4, l)];
        uint2 e5 = csr[min(s0 + 5, l)];
        uint2 e6 = csr[min(s0 + 6, l)];
        uint2 e7 = csr[min(s0 + 7, l)];
        ushort4 h4 = xs[(size_t)min(e4.x, nm1) * 16 + d4];
        ushort4 h5 = xs[(size_t)min(e5.x, nm1) * 16 + d4];
        ushort4 h6 = xs[(size_t)min(e6.x, nm1) * 16 + d4];
        ushort4 h7 = xs[(size_t)min(e7.x, nm1) * 16 + d4];
        {   // round 0 accum happens here so its wait overlaps h4..h7 flight
            const float g0 = (s0     < s1) ? 1.0f : 0.0f;
            const float g1 = (s0 + 1 < s1) ? 1.0f : 0.0f;
            const float g2 = (s0 + 2 < s1) ? 1.0f : 0.0f;
            const float g3 = (s0 + 3 < s1) ? 1.0f : 0.0f;
            float4 w0 = edge_w4(fa.y, aw, rw);
            float4 w1 = edge_w4(fa.w, aw, rw);
            float4 w2 = edge_w4(fb.y, aw, rw);
            float4 w3 = edge_w4(fb.w, aw, rw);
            acc4(num, den, w0, h0, g0);
            acc4(num, den, w1, h1, g1);
            acc4(num, den, w2, h2, g2);
            acc4(num, den, w3, h3, g3);
        }
        {
            const float g4 = (s0 + 4 < s1) ? 1.0f : 0.0f;
            const float g5 = (s0 + 5 < s1) ? 1.0f : 0.0f;
            const float g6 = (s0 + 6 < s1) ? 1.0f : 0.0f;
            const float g7 = (s0 + 7 < s1) ? 1.0f : 0.0f;
            float4 w4 = edge_w4(e4.y, aw, rw);
            float4 w5 = edge_w4(e5.y, aw, rw);
            float4 w6 = edge_w4(e6.y, aw, rw);
            float4 w7 = edge_w4(e7.y, aw, rw);
            acc4(num, den, w4, h4, g4);
            acc4(num, den, w5, h5, g5);
            acc4(num, den, w6, h6, g6);
            acc4(num, den, w7, h7, g7);
        }
        // rare deg>8 tail (~1.8% of nodes)
        for (int i = s0 + 8; i < s1; i += 4) {
            const int last = s1 - 1;
            uint2 e0 = csr[i];
            uint2 e1 = csr[min(i + 1, last)];
            uint2 e2 = csr[min(i + 2, last)];
            uint2 e3 = csr[min(i + 3, last)];
            ushort4 t0 = xs[(size_t)e0.x * 16 + d4];
            ushort4 t1 = xs[(size_t)e1.x * 16 + d4];
            ushort4 t2 = xs[(size_t)e2.x * 16 + d4];
            ushort4 t3 = xs[(size_t)e3.x * 16 + d4];
            float4 w0 = edge_w4(e0.y, aw, rw);
            float4 w1 = edge_w4(e1.y, aw, rw);
            float4 w2 = edge_w4(e2.y, aw, rw);
            float4 w3 = edge_w4(e3.y, aw, rw);
            float g1 = (i + 1 < s1) ? 1.0f : 0.0f;
            float g2 = (i + 2 < s1) ? 1.0f : 0.0f;
            float g3 = (i + 3 < s1) ? 1.0f : 0.0f;
            acc4(num, den, w0, t0, 1.0f);
            acc4(num, den, w1, t1, g1);
            acc4(num, den, w2, t2, g2);
            acc4(num, den, w3, t3, g3);
        }
    } else {
        // deg<=4 fast path (89% of nodes): one gather round trip total
        const float g0 = (s0     < s1) ? 1.0f : 0.0f;
        const float g1 = (s0 + 1 < s1) ? 1.0f : 0.0f;
        const float g2 = (s0 + 2 < s1) ? 1.0f : 0.0f;
        const float g3 = (s0 + 3 < s1) ? 1.0f : 0.0f;
        float4 w0 = edge_w4(fa.y, aw, rw);
        float4 w1 = edge_w4(fa.w, aw, rw);
        float4 w2 = edge_w4(fb.y, aw, rw);
        float4 w3 = edge_w4(fb.w, aw, rw);
        acc4(num, den, w0, h0, g0);
        acc4(num, den, w1, h1, g1);
        acc4(num, den, w2, h2, g2);
        acc4(num, den, w3, h3, g3);
    }

    // ---- epilogue ----
    float4 xr;   // raw ratio, before dinv[v] scaling
    xr.x = num.x / (den.x + 1e-16f);
    xr.y = num.y / (den.y + 1e-16f);
    xr.z = num.z / (den.z + 1e-16f);
    xr.w = num.w / (den.w + 1e-16f);
    const int dv = s1 - s0;
    const float dinv = (dv > 0) ? rsqrtf((float)dv) : 0.0f;
    if (MODE == 2) {
        const float sd = (dv > 0) ? sqrtf((float)dv) : 0.0f;
        float4 r;
        r.x = (emb_v.x + sd * (Av.x + Bv.x) + dinv * xr.x) * 0.25f;
        r.y = (emb_v.y + sd * (Av.y + Bv.y) + dinv * xr.y) * 0.25f;
        r.z = (emb_v.z + sd * (Av.z + Bv.z) + dinv * xr.z) * 0.25f;
        r.w = (emb_v.w + sd * (Av.w + Bv.w) + dinv * xr.w) * 0.25f;
        out4[o] = r;
    } else {
        const float s = dinv * dinv;   // store dinv[v] * x_new = dinv^2 * xr
        xsout[o] = pack4(make_float4(s * xr.x, s * xr.y, s * xr.z, s * xr.w));
    }
}

// ---------------- launch ----------------

extern "C" void kernel_launch(void* const* d_in, const int* in_sizes, int n_in,
                              void* d_out, int out_size, void* d_ws, size_t ws_size,
                              hipStream_t stream) {
    const int*   ei    = (const int*)d_in[0];
    const float* attrs = (const float*)d_in[1];
    const float* emb   = (const float*)d_in[2];
    const float* a_att = (const float*)d_in[3];
    const float* r_att = (const float*)d_in[4];

    const int E = in_sizes[0] / 2;
    const int N = in_sizes[2] / 64;
    const int* src = ei;
    const int* dst = ei + E;

    char* ws = (char*)d_ws;
    size_t off = 0;
    auto alloc = [&](size_t bytes) {
        void* p = ws + off;
        off += (bytes + 255) & ~(size_t)255;
        return p;
    };
    int*     deg      = (int*)alloc((size_t)N * 4);
    int*     rank     = (int*)alloc((size_t)E * 4);
    int*     row_off  = (int*)alloc((size_t)(N + 1) * 4);
    int*     partials = (int*)alloc((size_t)BLK * 4);
    uint2*   csr      = (uint2*)alloc((size_t)E * 8);
    uint2*   f4tab    = (uint2*)alloc((size_t)N * 4 * 8);
    ushort4* embs     = (ushort4*)alloc((size_t)N * 16 * 8);
    ushort4* xsA      = (ushort4*)alloc((size_t)N * 16 * 8);
    ushort4* xsB      = (ushort4*)alloc((size_t)N * 16 * 8);
    float4*  out      = (float4*)d_out;

    hipMemsetAsync(deg, 0, (size_t)N * 4, stream);
    hipMemsetAsync(f4tab, 0, (size_t)N * 4 * 8, stream);

    int gE = (E + BLK - 1) / BLK;
    int nb = (N + CH - 1) / CH;                 // 196 for N=200000 (must be <= 256)
    int gF = gE;
    int gC = (N * 16 + BLK - 1) / BLK;

    k_deg     <<<gE, BLK, 0, stream>>>(dst, deg, rank, E);
    k_scan1   <<<nb, BLK, 0, stream>>>(deg, partials, N);
    k_scan2   <<<nb, BLK, 0, stream>>>(deg, partials, row_off, N, E, nb);
    k_convfill<<<gF + gC, BLK, 0, stream>>>(src, dst, (const float2*)attrs, row_off,
                                            rank, deg, csr, f4tab, (const float4*)emb,
                                            embs, E, N * 16, gF);

    const float4* emb4 = (const float4*)emb;
    const float4* aw4  = (const float4*)a_att;
    const float4* rw4  = (const float4*)r_att;

    int gL = (N + (LBLK / 16) - 1) / (LBLK / 16);
    k_layer<0><<<gL, LBLK, 0, stream>>>(embs, csr, f4tab, row_off, aw4,      rw4,
                                        nullptr, nullptr, nullptr, xsA, nullptr, N);
    k_layer<1><<<gL, LBLK, 0, stream>>>(xsA,  csr, f4tab, row_off, aw4 + 16, rw4 + 16,
                                        nullptr, nullptr, nullptr, xsB, nullptr, N);
    k_layer<2><<<gL, LBLK, 0, stream>>>(xsB,  csr, f4tab, row_off, aw4 + 32, rw4 + 32,
                                        emb4, xsA, xsB, nullptr, out, N);
}

// Round 4
// 253.725 us; speedup vs baseline: 1.1030x; 1.1030x over previous
//
#include <hip/hip_runtime.h>

#define BLK 256
#define LBLK 256   // layer kernel: 8 threads per node, 32 nodes/block
#define CH 1024    // scan chunk per block (N=200000 -> 196 blocks, <= 256)

// ---------------- bf16 helpers ----------------
__device__ __forceinline__ unsigned short f2bf(float f) {
    unsigned u = __float_as_uint(f);
    u += 0x7FFFu + ((u >> 16) & 1u);       // round-to-nearest-even
    return (unsigned short)(u >> 16);
}
__device__ __forceinline__ float bf2f(unsigned short h) {
    return __uint_as_float((unsigned)h << 16);
}
__device__ __forceinline__ float4 unpack4(ushort4 h) {
    return make_float4(bf2f(h.x), bf2f(h.y), bf2f(h.z), bf2f(h.w));
}
__device__ __forceinline__ ushort4 pack4(float4 f) {
    ushort4 h; h.x = f2bf(f.x); h.y = f2bf(f.y); h.z = f2bf(f.z); h.w = f2bf(f.w);
    return h;
}
// 4 bf16 packed in uint2 -> float4 (low ushort = even dim)
__device__ __forceinline__ float4 unpack4u(uint2 u) {
    return make_float4(__uint_as_float(u.x << 16), __uint_as_float(u.x & 0xffff0000u),
                       __uint_as_float(u.y << 16), __uint_as_float(u.y & 0xffff0000u));
}
__device__ __forceinline__ unsigned pack2(float lo, float hi) {
    return (unsigned)f2bf(lo) | ((unsigned)f2bf(hi) << 16);
}

// ---------------- setup kernels (identical to best round-0 version) ----------------

__global__ void k_deg(const int* __restrict__ dst, int* __restrict__ deg,
                      int* __restrict__ rank, int E) {
    int e = blockIdx.x * blockDim.x + threadIdx.x;
    if (e < E) rank[e] = atomicAdd(&deg[dst[e]], 1);
}

__global__ void k_scan1(const int* __restrict__ deg, int* __restrict__ partials, int N) {
    __shared__ int sm[BLK];
    int i0 = blockIdx.x * CH + threadIdx.x * 4;
    int s = 0;
    if (i0 + 3 < N) {
        int4 v = *(const int4*)(deg + i0);
        s = (v.x + v.y) + (v.z + v.w);
    } else {
        for (int k = 0; k < 4; ++k) if (i0 + k < N) s += deg[i0 + k];
    }
    sm[threadIdx.x] = s;
    __syncthreads();
    for (int off = BLK / 2; off > 0; off >>= 1) {
        if (threadIdx.x < off) sm[threadIdx.x] += sm[threadIdx.x + off];
        __syncthreads();
    }
    if (threadIdx.x == 0) partials[blockIdx.x] = sm[0];
}

__global__ void k_scan2(const int* __restrict__ deg, const int* __restrict__ partials,
                        int* __restrict__ row_off, int N, int E, int nb) {
    __shared__ int sp[BLK];
    __shared__ int sm[BLK];
    int b = blockIdx.x, t = threadIdx.x;
    sp[t] = (t < nb) ? partials[t] : 0;
    __syncthreads();
    for (int off = 1; off < BLK; off <<= 1) {
        int add = (t >= off) ? sp[t - off] : 0;
        __syncthreads();
        sp[t] += add;
        __syncthreads();
    }
    int base = (b == 0) ? 0 : sp[b - 1];
    if (b == 0 && t == 0) row_off[N] = E;
    int i0 = b * CH + t * 4;
    int v0 = 0, v1 = 0, v2 = 0, v3 = 0;
    if (i0 + 3 < N) {
        int4 v = *(const int4*)(deg + i0);
        v0 = v.x; v1 = v.y; v2 = v.z; v3 = v.w;
    } else {
        if (i0     < N) v0 = deg[i0];
        if (i0 + 1 < N) v1 = deg[i0 + 1];
        if (i0 + 2 < N) v2 = deg[i0 + 2];
    }
    int tot = (v0 + v1) + (v2 + v3);
    sm[t] = tot;
    __syncthreads();
    for (int off = 1; off < BLK; off <<= 1) {
        int add = (t >= off) ? sm[t - off] : 0;
        __syncthreads();
        sm[t] += add;
        __syncthreads();
    }
    int excl = base + sm[t] - tot;
    int4 r;
    r.x = excl;
    r.y = excl + v0;
    r.z = excl + v0 + v1;
    r.w = excl + v0 + v1 + v2;
    if (i0 + 3 < N) {
        *(int4*)(row_off + i0) = r;
    } else {
        if (i0     < N) row_off[i0]     = r.x;
        if (i0 + 1 < N) row_off[i0 + 1] = r.y;
        if (i0 + 2 < N) row_off[i0 + 2] = r.z;
    }
}

__global__ void k_convfill(const int* __restrict__ src, const int* __restrict__ dst,
                           const float2* __restrict__ attrs, const int* __restrict__ row_off,
                           const int* __restrict__ rank, const int* __restrict__ deg,
                           uint2* __restrict__ csr, const float4* __restrict__ emb4,
                           ushort4* __restrict__ embs, int E, int N16, int gF) {
    int b = blockIdx.x;
    if (b < gF) {
        int e = b * BLK + threadIdx.x;
        if (e >= E) return;
        int pos = row_off[dst[e]] + rank[e];
        float2 ar = attrs[e];
        csr[pos] = make_uint2((unsigned)src[e],
                              (unsigned)f2bf(ar.x) | ((unsigned)f2bf(ar.y) << 16));
    } else {
        int i = (b - gF) * BLK + threadIdx.x;
        if (i >= N16) return;
        int d = deg[i >> 4];
        float dinv = (d > 0) ? rsqrtf((float)d) : 0.0f;
        float4 e = emb4[i];
        embs[i] = pack4(make_float4(dinv * e.x, dinv * e.y, dinv * e.z, dinv * e.w));
    }
}

// ---------------- per-layer kernel ----------------
// 8 threads per node, 8 dims each (uint4 = 8 bf16, 16 B/lane; a node-group's
// 8 lanes still cover one full 128-B row -> one coalesced request).
// vs round 0 (16 lanes/node): each wave carries EIGHT independent node chains
// instead of four -> 2x outstanding csr->gather requests per wave, same
// per-lane register/loop pattern the compiler scheduled well at VGPR 36.
// Waves: 25k (from 50k). Traffic and per-dim arithmetic identical.
// xs rows PRE-SCALED by dinv[src].
// x_new[v] = dinv[v] * (Σ w·xs[src]) / (Σ w + eps)

__device__ __forceinline__ float lrelu(float x) { return fmaxf(x, 0.01f * x); }

// 8 weights for one edge (shared a,r extraction)
__device__ __forceinline__ void edge_w8(unsigned ar,
                                        const float4& awl, const float4& awh,
                                        const float4& rwl, const float4& rwh,
                                        float4& wl, float4& wh) {
    float a = bf2f((unsigned short)(ar & 0xffffu));
    float r = bf2f((unsigned short)(ar >> 16));
    wl.x = __expf(lrelu(a * awl.x) + lrelu(r * rwl.x));
    wl.y = __expf(lrelu(a * awl.y) + lrelu(r * rwl.y));
    wl.z = __expf(lrelu(a * awl.z) + lrelu(r * rwl.z));
    wl.w = __expf(lrelu(a * awl.w) + lrelu(r * rwl.w));
    wh.x = __expf(lrelu(a * awh.x) + lrelu(r * rwh.x));
    wh.y = __expf(lrelu(a * awh.y) + lrelu(r * rwh.y));
    wh.z = __expf(lrelu(a * awh.z) + lrelu(r * rwh.z));
    wh.w = __expf(lrelu(a * awh.w) + lrelu(r * rwh.w));
}

__device__ __forceinline__ void acc4u(float4& num, float4& den,
                                      const float4& w, uint2 xu, float g) {
    float4 x = unpack4u(xu);
    den.x += g * w.x; den.y += g * w.y; den.z += g * w.z; den.w += g * w.w;
    num.x += g * w.x * x.x;
    num.y += g * w.y * x.y;
    num.z += g * w.z * x.z;
    num.w += g * w.w * x.w;
}

__device__ __forceinline__ void acc8(float4& numl, float4& denl,
                                     float4& numh, float4& denh,
                                     const float4& wl, const float4& wh,
                                     const uint4& h, float g) {
    acc4u(numl, denl, wl, make_uint2(h.x, h.y), g);
    acc4u(numh, denh, wh, make_uint2(h.z, h.w), g);
}

template<int MODE>
__global__ __launch_bounds__(LBLK) void k_layer(
    const uint4* __restrict__ xs8, const uint2* __restrict__ csr,
    const int* __restrict__ row_off,
    const float4* __restrict__ aw4, const float4* __restrict__ rw4,
    const float4* __restrict__ emb4,
    const uint4* __restrict__ xsA8, const uint4* __restrict__ xsB8,
    uint4* __restrict__ xsout8, float4* __restrict__ out4, int N) {
    const int t = threadIdx.x;
    const int d8 = t & 7;
    const int v = blockIdx.x * (LBLK / 8) + (t >> 3);
    if (v >= N) return;

    const float4 awl = aw4[2 * d8],     rwl = rw4[2 * d8];
    const float4 awh = aw4[2 * d8 + 1], rwh = rw4[2 * d8 + 1];
    const int s0 = row_off[v];
    const int s1 = row_off[v + 1];

    float4 numl = {0.f, 0.f, 0.f, 0.f}, denl = {0.f, 0.f, 0.f, 0.f};
    float4 numh = {0.f, 0.f, 0.f, 0.f}, denh = {0.f, 0.f, 0.f, 0.f};

    for (int i = s0; i < s1; i += 4) {
        const int last = s1 - 1;
        uint2 e0 = csr[i];
        uint2 e1 = csr[min(i + 1, last)];
        uint2 e2 = csr[min(i + 2, last)];
        uint2 e3 = csr[min(i + 3, last)];
        uint4 h0 = xs8[(size_t)e0.x * 8 + d8];
        uint4 h1 = xs8[(size_t)e1.x * 8 + d8];
        uint4 h2 = xs8[(size_t)e2.x * 8 + d8];
        uint4 h3 = xs8[(size_t)e3.x * 8 + d8];
        float4 w0l, w0h, w1l, w1h, w2l, w2h, w3l, w3h;
        edge_w8(e0.y, awl, awh, rwl, rwh, w0l, w0h);
        edge_w8(e1.y, awl, awh, rwl, rwh, w1l, w1h);
        edge_w8(e2.y, awl, awh, rwl, rwh, w2l, w2h);
        edge_w8(e3.y, awl, awh, rwl, rwh, w3l, w3h);
        float g1 = (i + 1 < s1) ? 1.0f : 0.0f;
        float g2 = (i + 2 < s1) ? 1.0f : 0.0f;
        float g3 = (i + 3 < s1) ? 1.0f : 0.0f;
        acc8(numl, denl, numh, denh, w0l, w0h, h0, 1.0f);
        acc8(numl, denl, numh, denh, w1l, w1h, h1, g1);
        acc8(numl, denl, numh, denh, w2l, w2h, h2, g2);
        acc8(numl, denl, numh, denh, w3l, w3h, h3, g3);
    }

    float4 xr0, xr1;   // raw ratio, before dinv[v] scaling
    xr0.x = numl.x / (denl.x + 1e-16f);
    xr0.y = numl.y / (denl.y + 1e-16f);
    xr0.z = numl.z / (denl.z + 1e-16f);
    xr0.w = numl.w / (denl.w + 1e-16f);
    xr1.x = numh.x / (denh.x + 1e-16f);
    xr1.y = numh.y / (denh.y + 1e-16f);
    xr1.z = numh.z / (denh.z + 1e-16f);
    xr1.w = numh.w / (denh.w + 1e-16f);
    const int dv = s1 - s0;
    const float dinv = (dv > 0) ? rsqrtf((float)dv) : 0.0f;
    if (MODE == 2) {
        const float sd = (dv > 0) ? sqrtf((float)dv) : 0.0f;
        const size_t of = (size_t)v * 16 + 2 * d8;   // float4 index
        const size_t o8 = (size_t)v * 8 + d8;        // uint4 (8-bf16) index
        float4 e0 = emb4[of];
        float4 e1 = emb4[of + 1];
        uint4 Au = xsA8[o8];
        uint4 Bu = xsB8[o8];
        float4 A0 = unpack4u(make_uint2(Au.x, Au.y));
        float4 A1 = unpack4u(make_uint2(Au.z, Au.w));
        float4 B0 = unpack4u(make_uint2(Bu.x, Bu.y));
        float4 B1 = unpack4u(make_uint2(Bu.z, Bu.w));
        float4 r0, r1;
        r0.x = (e0.x + sd * (A0.x + B0.x) + dinv * xr0.x) * 0.25f;
        r0.y = (e0.y + sd * (A0.y + B0.y) + dinv * xr0.y) * 0.25f;
        r0.z = (e0.z + sd * (A0.z + B0.z) + dinv * xr0.z) * 0.25f;
        r0.w = (e0.w + sd * (A0.w + B0.w) + dinv * xr0.w) * 0.25f;
        r1.x = (e1.x + sd * (A1.x + B1.x) + dinv * xr1.x) * 0.25f;
        r1.y = (e1.y + sd * (A1.y + B1.y) + dinv * xr1.y) * 0.25f;
        r1.z = (e1.z + sd * (A1.z + B1.z) + dinv * xr1.z) * 0.25f;
        r1.w = (e1.w + sd * (A1.w + B1.w) + dinv * xr1.w) * 0.25f;
        out4[of]     = r0;
        out4[of + 1] = r1;
    } else {
        const float s = dinv * dinv;   // store dinv[v] * x_new = dinv^2 * xr
        uint4 pkt;
        pkt.x = pack2(s * xr0.x, s * xr0.y);
        pkt.y = pack2(s * xr0.z, s * xr0.w);
        pkt.z = pack2(s * xr1.x, s * xr1.y);
        pkt.w = pack2(s * xr1.z, s * xr1.w);
        xsout8[(size_t)v * 8 + d8] = pkt;
    }
}

// ---------------- launch ----------------

extern "C" void kernel_launch(void* const* d_in, const int* in_sizes, int n_in,
                              void* d_out, int out_size, void* d_ws, size_t ws_size,
                              hipStream_t stream) {
    const int*   ei    = (const int*)d_in[0];
    const float* attrs = (const float*)d_in[1];
    const float* emb   = (const float*)d_in[2];
    const float* a_att = (const float*)d_in[3];
    const float* r_att = (const float*)d_in[4];

    const int E = in_sizes[0] / 2;
    const int N = in_sizes[2] / 64;
    const int* src = ei;
    const int* dst = ei + E;

    char* ws = (char*)d_ws;
    size_t off = 0;
    auto alloc = [&](size_t bytes) {
        void* p = ws + off;
        off += (bytes + 255) & ~(size_t)255;
        return p;
    };
    int*     deg      = (int*)alloc((size_t)N * 4);
    int*     rank     = (int*)alloc((size_t)E * 4);
    int*     row_off  = (int*)alloc((size_t)(N + 1) * 4);
    int*     partials = (int*)alloc((size_t)BLK * 4);
    uint2*   csr      = (uint2*)alloc((size_t)E * 8);
    ushort4* embs     = (ushort4*)alloc((size_t)N * 16 * 8);
    ushort4* xsA      = (ushort4*)alloc((size_t)N * 16 * 8);
    ushort4* xsB      = (ushort4*)alloc((size_t)N * 16 * 8);
    float4*  out      = (float4*)d_out;

    hipMemsetAsync(deg, 0, (size_t)N * 4, stream);

    int gE = (E + BLK - 1) / BLK;
    int nb = (N + CH - 1) / CH;                 // 196 for N=200000 (must be <= 256)
    int gF = gE;
    int gC = (N * 16 + BLK - 1) / BLK;

    k_deg     <<<gE, BLK, 0, stream>>>(dst, deg, rank, E);
    k_scan1   <<<nb, BLK, 0, stream>>>(deg, partials, N);
    k_scan2   <<<nb, BLK, 0, stream>>>(deg, partials, row_off, N, E, nb);
    k_convfill<<<gF + gC, BLK, 0, stream>>>(src, dst, (const float2*)attrs, row_off,
                                            rank, deg, csr, (const float4*)emb,
                                            embs, E, N * 16, gF);

    const float4* emb4 = (const float4*)emb;
    const float4* aw4  = (const float4*)a_att;
    const float4* rw4  = (const float4*)r_att;

    int gL = (N + (LBLK / 8) - 1) / (LBLK / 8);
    k_layer<0><<<gL, LBLK, 0, stream>>>((const uint4*)embs, csr, row_off, aw4,      rw4,
                                        nullptr, nullptr, nullptr, (uint4*)xsA, nullptr, N);
    k_layer<1><<<gL, LBLK, 0, stream>>>((const uint4*)xsA,  csr, row_off, aw4 + 16, rw4 + 16,
                                        nullptr, nullptr, nullptr, (uint4*)xsB, nullptr, N);
    k_layer<2><<<gL, LBLK, 0, stream>>>((const uint4*)xsB,  csr, row_off, aw4 + 32, rw4 + 32,
                                        emb4, (const uint4*)xsA, (const uint4*)xsB,
                                        nullptr, out, N);
}